// Round 8
// baseline (154.039 us; speedup 1.0000x reference)
//
#include <hip/hip_runtime.h>
#include <math.h>

typedef _Float16 f16;
typedef f16 f16x8 __attribute__((ext_vector_type(8)));
typedef float f32x16 __attribute__((ext_vector_type(16)));
typedef unsigned short u16;
typedef unsigned int u32;

#define B_ 2
#define C_ 64
#define KS 5             // K-steps of 16: 64 feats + mask(k=64) + bias(k=65) + pad
#define H_ 112
#define W_ 112
#define N_ 12544
#define S_ 50
#define G_ 120
#define MT 392           // m-tiles of 32
#define NT 392           // n-subtiles of 32
#define SPLIT 8
#define TPS 49           // m-tiles per split
#define LCAP 4           // per-lane-half top-4 (exact, branch-free)
#define CPR (SPLIT*2*LCAP) // 64 candidates per row -> 1 per lane in rescore

#define NEGINF (-__builtin_inff())

union U16B { uint4 u; f16x8 h; f16 e[8]; };

// ---------------------------------------------------------------------------
// Kernel 0: bool-mask format detect (byte vs int32), vectorized word test.
// ---------------------------------------------------------------------------
__global__ void detect_fmt(const u32* __restrict__ m1, const u32* __restrict__ m2,
                           int nw, int* __restrict__ flags) {
    __shared__ u32 s[2];
    if (threadIdx.x == 0) { s[0] = 0; s[1] = 0; }
    __syncthreads();
    u32 a = 0, bb = 0;
    for (int i = threadIdx.x; i < nw; i += blockDim.x) {
        a  |= m1[i] & 0xFFFFFF00u;
        bb |= m2[i] & 0xFFFFFF00u;
    }
    if (a)  atomicOr(&s[0], 1u);
    if (bb) atomicOr(&s[1], 1u);
    __syncthreads();
    if (threadIdx.x == 0) { flags[0] = s[0] ? 1 : 0; flags[1] = s[1] ? 1 : 0; }
}

// ---------------------------------------------------------------------------
// Kernel 1 (fused): blockIdx.y==0 -> src features: fp16 frag-ordered fxq
// (k=64/65 channels = 1.0) AND contiguous fp32 fxT rows (for rescore's
// exact re-dot; same values, contiguous layout).  blockIdx.y==1 -> dst
// features: fp32 fynT rows (bitwise same math as round 1), fp16 frag-ordered
// fynq with mask channel (k=64: 0 valid / -96 masked) and bias channel
// (k=65: +128 -> all stage1 scores positive), nyeps, minf.
// ---------------------------------------------------------------------------
__global__ void prep(const float* __restrict__ fx, const float* __restrict__ fy,
                     const unsigned char* __restrict__ mask2b,
                     const int* __restrict__ flags,
                     f16* __restrict__ fxq, float* __restrict__ fxT,
                     float* __restrict__ fynT, f16* __restrict__ fynq,
                     float* __restrict__ nyeps, float* __restrict__ minf) {
    int t = blockIdx.x * blockDim.x + threadIdx.x;   // t = b*N + pixel
    if (t >= B_ * N_) return;
    int b = t / N_, m = t - b * N_;
    int tile = m >> 5, r = m & 31;

    if (blockIdx.y == 0) {
        const float* src = fx + (size_t)b * C_ * N_ + m;
        float v[64];
        #pragma unroll
        for (int c = 0; c < C_; ++c) v[c] = src[(size_t)c * N_];

        float4* xT = (float4*)(fxT + (size_t)t * C_);
        #pragma unroll
        for (int c4 = 0; c4 < 16; ++c4)
            xT[c4] = make_float4(v[c4*4], v[c4*4+1], v[c4*4+2], v[c4*4+3]);

        uint4* q4 = (uint4*)fxq;
        size_t cb = (size_t)(b * NT + tile) * KS * 64;
        #pragma unroll
        for (int ks = 0; ks < KS; ++ks) {
            #pragma unroll
            for (int hi = 0; hi < 2; ++hi) {
                U16B tmp;
                #pragma unroll
                for (int i = 0; i < 8; ++i) {
                    int k = 16 * ks + 8 * hi + i;
                    float val = (k < 64) ? v[k] : ((k <= 65) ? 1.0f : 0.0f);
                    tmp.e[i] = (f16)val;
                }
                q4[cb + (size_t)ks * 64 + hi * 32 + r] = tmp.u;
            }
        }
    } else {
        const float* src = fy + (size_t)b * C_ * N_ + m;
        float v[64];
        float ss = 0.f;
        #pragma unroll
        for (int c = 0; c < C_; ++c) { v[c] = src[(size_t)c * N_]; ss = fmaf(v[c], v[c], ss); }
        float ny = sqrtf(ss) + 1e-12f;
        nyeps[t] = ny;
        bool valid = flags[1] ? (mask2b[t] != 0) : (((const int*)mask2b)[t] != 0);
        minf[t] = valid ? 0.0f : NEGINF;
        float mval = valid ? 0.0f : -96.0f;

        float* dT = fynT + (size_t)t * C_;
        #pragma unroll
        for (int c = 0; c < C_; ++c) dT[c] = v[c] / ny;   // round-1 arithmetic

        uint4* q4 = (uint4*)fynq;
        size_t cb = (size_t)(b * MT + tile) * KS * 64;
        #pragma unroll
        for (int ks = 0; ks < KS; ++ks) {
            #pragma unroll
            for (int hi = 0; hi < 2; ++hi) {
                U16B tmp;
                #pragma unroll
                for (int i = 0; i < 8; ++i) {
                    int k = 16 * ks + 8 * hi + i;
                    float val = (k < 64) ? (v[k] / ny)
                              : ((k == 64) ? mval : ((k == 65) ? 128.0f : 0.0f));
                    tmp.e[i] = (f16)val;
                }
                q4[cb + (size_t)ks * 64 + hi * 32 + r] = tmp.u;
            }
        }
    }
}

// ---------------------------------------------------------------------------
// Kernel 2: MFMA candidate pass — branch-free, explicitly software-pipelined.
// Ping-pong accumulators: cell t's MFMAs are issued BEFORE cell t-1's
// extraction, so the ~190-cycle VALU extraction hides MFMA pipe latency and
// the prefetched A-tile load latency within a single wave. Scores positive
// (bias +128 channel) -> f32 order == u32 order; pack 10-bit (tile*16+reg)
// into mantissa low bits via v_and_or_b32 (VGPR mask + SGPR idx, 1 op),
// then a med3 chain keeps the EXACT top-4 packed values of the lane-half's
// 784-value stream. Coverage: a true row-top-3 ranks <=3 within its
// lane-half stream (noise ~0.02 absorbed by rescore's 0.125 recheck band).
// ---------------------------------------------------------------------------
#define LDA(dst, t) { _Pragma("unroll") \
    for (int ks = 0; ks < KS; ++ks) { \
        U16B u_; u_.u = fyb[((size_t)(t) * KS + ks) * 64]; dst[ks] = u_.h; } }

#define MFMAC(acc, a) { acc = (f32x16){}; \
    _Pragma("unroll") \
    for (int ks = 0; ks < KS; ++ks) \
        acc = __builtin_amdgcn_mfma_f32_32x32x16_f16(a[ks], bfr[ks], acc, 0, 0, 0); }

#define EXTRACT(acc, t) { \
    u32 base_ = (u32)((t) * 16); \
    _Pragma("unroll") \
    for (int r = 0; r < 16; ++r) { \
        u32 pb_ = (__float_as_uint(acc[r]) & VMASK) | (base_ + (u32)r); \
        float p_ = __uint_as_float(pb_); \
        b4 = __builtin_amdgcn_fmed3f(p_, b3, b4); \
        b3 = __builtin_amdgcn_fmed3f(p_, b2, b3); \
        b2 = __builtin_amdgcn_fmed3f(p_, b1, b2); \
        b1 = fmaxf(p_, b1); } }

__global__ __launch_bounds__(256, 3)
void stage1(const f16* __restrict__ fxq, const f16* __restrict__ fynq,
            u32* __restrict__ cvals, u16* __restrict__ cidx) {
    const int tid = threadIdx.x;
    const int lane = tid & 63, w = tid >> 6;
    const int lo = lane & 31, hi = lane >> 5;
    const int nb = blockIdx.x;          // 0..97
    const int split = blockIdx.y;
    const int b = blockIdx.z;
    const int tbase = split * TPS;

    const uint4* fxq4 = (const uint4*)fxq;
    const uint4* fyb  = (const uint4*)fynq + ((size_t)(b * MT + tbase) * KS) * 64 + lane;

    // pack mask pinned in a VGPR so (bits & VMASK) | s_idx fuses to v_and_or_b32
    u32 VMASK;
    asm("v_mov_b32 %0, 0xFFFFFC00" : "=v"(VMASK));

    // resident B-fragments: fx for this wave's n-subtile
    const int nt = nb * 4 + w;
    f16x8 bfr[KS];
    #pragma unroll
    for (int ks = 0; ks < KS; ++ks) {
        U16B u; u.u = fxq4[((size_t)((b * NT + nt) * KS + ks)) * 64 + lane];
        bfr[ks] = u.h;
    }

    float b1 = 0.f, b2 = 0.f, b3 = 0.f, b4 = 0.f;

    f16x8 aA[KS], aB[KS];
    f32x16 accA, accB;

    LDA(aA, 0);
    MFMAC(accA, aA);                     // cell 0 in flight
    LDA(aB, 1);

    #pragma unroll 1
    for (int t = 1; t < TPS; t += 2) {   // t = 1,3,...,47
        MFMAC(accB, aB);                 // cell t in flight
        LDA(aA, t + 1);                  // prefetch cell t+1 (<= 48)
        EXTRACT(accA, t - 1);            // extract cell t-1 (hides latency)
        MFMAC(accA, aA);                 // cell t+1 in flight
        if (t + 2 < TPS) LDA(aB, t + 2); // prefetch cell t+2
        EXTRACT(accB, t);                // extract cell t
    }
    EXTRACT(accA, TPS - 1);              // cell 48

    // decode + write candidates: [b][n][split][hi][4]
    int n = nt * 32 + lo;
    size_t base = (((size_t)(b * N_ + n) * SPLIT + split) * 2 + hi) * LCAP;
    float bs[4] = {b1, b2, b3, b4};
    #pragma unroll
    for (int k = 0; k < 4; ++k) {
        u32 pb = __float_as_uint(bs[k]);
        int idx10 = (int)(pb & 1023u);
        int tl = idx10 >> 4, r = idx10 & 15;
        int m = (tbase + tl) * 32 + (r & 3) + ((r >> 2) << 3) + (hi << 2);
        cvals[base + k] = pb;
        cidx[base + k] = (u16)m;
    }
}

// ---------------------------------------------------------------------------
// Kernel 3: selective exact rescore. One wave per row, 1 candidate/lane.
// 3 wave-max rounds on noisy packed values -> t3 (duplicate knockout only
// lowers t3 -> band only widens); lanes with vn >= t3 - 0.125 (noise+grain
// ~0.04, 3x margin) recompute the bit-identical round-1 fp32 dot from the
// CONTIGUOUS fxT/fynT rows. Exact selection (tie: lower index) + exact
// weights -> absmax 0 preserved.
// ---------------------------------------------------------------------------
__global__ __launch_bounds__(256)
void rescore(const u32* __restrict__ cvals, const u16* __restrict__ cidx,
             const float* __restrict__ fxT, const float* __restrict__ fynT,
             const float* __restrict__ nyeps, const float* __restrict__ minf,
             const unsigned char* __restrict__ mask1b,
             const int* __restrict__ flags, float* __restrict__ out) {
    int gw = blockIdx.x * 4 + (threadIdx.x >> 6);    // row = b*N + n  (grid exact)
    int lane = threadIdx.x & 63;
    int b = gw / N_;

    float vn = __uint_as_float(cvals[(size_t)gw * CPR + lane]);
    int idx = cidx[(size_t)gw * CPR + lane];

    float cur = vn;
    float t3 = NEGINF;
    #pragma unroll
    for (int r = 0; r < 3; ++r) {
        float c = cur;
        #pragma unroll
        for (int off = 32; off >= 1; off >>= 1) c = fmaxf(c, __shfl_xor(c, off));
        t3 = c;
        cur = (cur == c) ? NEGINF : cur;
    }
    bool redo = (vn >= t3 - 0.125f);

    float rnk = NEGINF, wgt = 0.f;
    if (redo) {
        const float4* xq4 = (const float4*)(fxT + (size_t)gw * C_);
        const float4* fr4 = (const float4*)(fynT + ((size_t)b * N_ + idx) * C_);
        float a = 0.f;
        #pragma unroll
        for (int c4 = 0; c4 < 16; ++c4) {
            float4 xf = xq4[c4];
            float4 f  = fr4[c4];
            a = fmaf(xf.x, f.x, a);
            a = fmaf(xf.y, f.y, a);
            a = fmaf(xf.z, f.z, a);
            a = fmaf(xf.w, f.w, a);
        }
        rnk = a + minf[(size_t)b * N_ + idx];
        wgt = a * nyeps[(size_t)b * N_ + idx];
    }
    int midx = redo ? idx : 0x7fffffff;

    int wi[3]; float ww[3];
    #pragma unroll
    for (int r = 0; r < 3; ++r) {
        float cv = rnk; int ci = midx; float cw = wgt;
        #pragma unroll
        for (int off = 32; off >= 1; off >>= 1) {
            float ov = __shfl_xor(cv, off);
            int   oi = __shfl_xor(ci, off);
            float ow = __shfl_xor(cw, off);
            bool take = (ov > cv) || (ov == cv && oi < ci);
            cv = take ? ov : cv; ci = take ? oi : ci; cw = take ? ow : cw;
        }
        wi[r] = ci; ww[r] = cw;
        if (midx == ci) rnk = NEGINF;   // remove winner (and duplicates)
    }

    if (lane == 0) {
        float w0 = ww[0], w1 = ww[1], w2 = ww[2];
        float h0 = (float)(wi[0] / W_), h1 = (float)(wi[1] / W_), h2 = (float)(wi[2] / W_);
        float q0 = (float)(wi[0] % W_), q1 = (float)(wi[1] % W_), q2 = (float)(wi[2] % W_);
        float den = w0 + w1 + w2;
        float ph = (h0 * w0 + h1 * w1 + h2 * w2) / den;
        float pw = (q0 * w0 + q1 * w1 + q2 * w2) / den;
        bool m1 = flags[0] ? (mask1b[gw] != 0) : (((const int*)mask1b)[gw] != 0);
        out[2 * gw]     = m1 ? ph : -1.0f;
        out[2 * gw + 1] = m1 ? pw : -1.0f;
    }
}

// ---------------------------------------------------------------------------
// Kernel 4: slic gather.
// ---------------------------------------------------------------------------
__global__ void slic_gather(const float* __restrict__ spg,
                            const float* __restrict__ pred,
                            float* __restrict__ outg) {
    int t = blockIdx.x * blockDim.x + threadIdx.x;
    if (t >= B_ * S_ * G_) return;
    int b = t / (S_ * G_);
    float vh = spg[2 * t], vw = spg[2 * t + 1];
    int ph = (int)rintf(vh * (float)H_);
    int pw = (int)rintf(vw * (float)H_);
    ph = ph < 0 ? 0 : (ph > H_ - 1 ? H_ - 1 : ph);
    pw = pw < 0 ? 0 : (pw > H_ - 1 ? H_ - 1 : pw);
    int lin = ph * W_ + pw;
    outg[2 * t]     = pred[((size_t)b * N_ + lin) * 2]     / (float)H_;
    outg[2 * t + 1] = pred[((size_t)b * N_ + lin) * 2 + 1] / (float)H_;
}

extern "C" void kernel_launch(void* const* d_in, const int* in_sizes, int n_in,
                              void* d_out, int out_size, void* d_ws, size_t ws_size,
                              hipStream_t stream) {
    const float* img1 = (const float*)d_in[0];
    const float* img2 = (const float*)d_in[1];
    const void*  mask1 = d_in[2];
    const void*  mask2 = d_in[3];
    const float* spg = (const float*)d_in[4];
    float* out = (float*)d_out;

    char* ws = (char*)d_ws;
    size_t off = 0;
    int*   flags = (int*)(ws + off);            off += 256;
    float* fynT  = (float*)(ws + off);          off += (size_t)B_ * N_ * C_ * 4;       // 6.42 MB
    float* fxT   = (float*)(ws + off);          off += (size_t)B_ * N_ * C_ * 4;       // 6.42 MB
    f16*   fxq   = (f16*)(ws + off);            off += (size_t)B_ * NT * KS * 64 * 16; // 4.01 MB
    f16*   fynq  = (f16*)(ws + off);            off += (size_t)B_ * MT * KS * 64 * 16; // 4.01 MB
    float* nyeps = (float*)(ws + off);          off += (size_t)B_ * N_ * 4;
    float* minf  = (float*)(ws + off);          off += (size_t)B_ * N_ * 4;
    u32*   cvals = (u32*)(ws + off);            off += (size_t)B_ * N_ * CPR * 4;      // 6.42 MB
    u16*   cidx  = (u16*)(ws + off);            off += (size_t)B_ * N_ * CPR * 2;      // 3.21 MB

    detect_fmt<<<1, 1024, 0, stream>>>((const u32*)mask1, (const u32*)mask2,
                                       (B_ * N_) / 4, flags);
    dim3 gp((B_ * N_) / 256, 2);
    prep<<<gp, 256, 0, stream>>>(img1, img2, (const unsigned char*)mask2, flags,
                                 fxq, fxT, fynT, fynq, nyeps, minf);

    dim3 g1(98, SPLIT, B_);
    stage1<<<g1, 256, 0, stream>>>(fxq, fynq, cvals, cidx);

    rescore<<<(B_ * N_) / 4, 256, 0, stream>>>(
        cvals, cidx, fxT, fynT, nyeps, minf,
        (const unsigned char*)mask1, flags, out);

    slic_gather<<<(B_ * S_ * G_ + 255) / 256, 256, 0, stream>>>(
        spg, out, out + (size_t)B_ * N_ * 2);
}

// Round 9
// 153.935 us; speedup vs baseline: 1.0007x; 1.0007x over previous
//
#include <hip/hip_runtime.h>
#include <math.h>

typedef _Float16 f16;
typedef f16 f16x8 __attribute__((ext_vector_type(8)));
typedef float f32x16 __attribute__((ext_vector_type(16)));
typedef unsigned short u16;
typedef unsigned int u32;

#define B_ 2
#define C_ 64
#define KS 5             // K-steps of 16: 64 feats + mask(k=64) + bias(k=65) + pad
#define H_ 112
#define W_ 112
#define N_ 12544
#define S_ 50
#define G_ 120
#define MT 392           // m-tiles of 32
#define NT 392           // n-subtiles of 32
#define SPLIT 8
#define TPS 49           // m-tiles per split
#define LCAP 4           // per-lane-half top-4 (exact, branch-free)
#define CPR (SPLIT*2*LCAP) // 64 candidates per row -> 1 per lane in rescore

#define NEGINF (-__builtin_inff())

union U16B { uint4 u; f16x8 h; f16 e[8]; };

// ---------------------------------------------------------------------------
// Kernel 0: bool-mask format detect (byte vs int32), vectorized word test.
// ---------------------------------------------------------------------------
__global__ void detect_fmt(const u32* __restrict__ m1, const u32* __restrict__ m2,
                           int nw, int* __restrict__ flags) {
    __shared__ u32 s[2];
    if (threadIdx.x == 0) { s[0] = 0; s[1] = 0; }
    __syncthreads();
    u32 a = 0, bb = 0;
    for (int i = threadIdx.x; i < nw; i += blockDim.x) {
        a  |= m1[i] & 0xFFFFFF00u;
        bb |= m2[i] & 0xFFFFFF00u;
    }
    if (a)  atomicOr(&s[0], 1u);
    if (bb) atomicOr(&s[1], 1u);
    __syncthreads();
    if (threadIdx.x == 0) { flags[0] = s[0] ? 1 : 0; flags[1] = s[1] ? 1 : 0; }
}

// ---------------------------------------------------------------------------
// Kernel 1 (fused): y==0 -> src features: fp16 frag-ordered fxq (k=64/65
// channels = 1.0) AND contiguous fp32 fxT rows. y==1 -> dst features: fp32
// fynT rows (bitwise same math as round 1), fp16 frag-ordered fynq with
// mask channel (k=64: 0 valid / -96 masked) and bias channel (k=65: +128),
// nyeps, minf.
// ---------------------------------------------------------------------------
__global__ void prep(const float* __restrict__ fx, const float* __restrict__ fy,
                     const unsigned char* __restrict__ mask2b,
                     const int* __restrict__ flags,
                     f16* __restrict__ fxq, float* __restrict__ fxT,
                     float* __restrict__ fynT, f16* __restrict__ fynq,
                     float* __restrict__ nyeps, float* __restrict__ minf) {
    int t = blockIdx.x * blockDim.x + threadIdx.x;   // t = b*N + pixel
    if (t >= B_ * N_) return;
    int b = t / N_, m = t - b * N_;
    int tile = m >> 5, r = m & 31;

    if (blockIdx.y == 0) {
        const float* src = fx + (size_t)b * C_ * N_ + m;
        float v[64];
        #pragma unroll
        for (int c = 0; c < C_; ++c) v[c] = src[(size_t)c * N_];

        float4* xT = (float4*)(fxT + (size_t)t * C_);
        #pragma unroll
        for (int c4 = 0; c4 < 16; ++c4)
            xT[c4] = make_float4(v[c4*4], v[c4*4+1], v[c4*4+2], v[c4*4+3]);

        uint4* q4 = (uint4*)fxq;
        size_t cb = (size_t)(b * NT + tile) * KS * 64;
        #pragma unroll
        for (int ks = 0; ks < KS; ++ks) {
            #pragma unroll
            for (int hi = 0; hi < 2; ++hi) {
                U16B tmp;
                #pragma unroll
                for (int i = 0; i < 8; ++i) {
                    int k = 16 * ks + 8 * hi + i;
                    float val = (k < 64) ? v[k] : ((k <= 65) ? 1.0f : 0.0f);
                    tmp.e[i] = (f16)val;
                }
                q4[cb + (size_t)ks * 64 + hi * 32 + r] = tmp.u;
            }
        }
    } else {
        const float* src = fy + (size_t)b * C_ * N_ + m;
        float v[64];
        float ss = 0.f;
        #pragma unroll
        for (int c = 0; c < C_; ++c) { v[c] = src[(size_t)c * N_]; ss = fmaf(v[c], v[c], ss); }
        float ny = sqrtf(ss) + 1e-12f;
        nyeps[t] = ny;
        bool valid = flags[1] ? (mask2b[t] != 0) : (((const int*)mask2b)[t] != 0);
        minf[t] = valid ? 0.0f : NEGINF;
        float mval = valid ? 0.0f : -96.0f;

        float* dT = fynT + (size_t)t * C_;
        #pragma unroll
        for (int c = 0; c < C_; ++c) dT[c] = v[c] / ny;   // round-1 arithmetic

        uint4* q4 = (uint4*)fynq;
        size_t cb = (size_t)(b * MT + tile) * KS * 64;
        #pragma unroll
        for (int ks = 0; ks < KS; ++ks) {
            #pragma unroll
            for (int hi = 0; hi < 2; ++hi) {
                U16B tmp;
                #pragma unroll
                for (int i = 0; i < 8; ++i) {
                    int k = 16 * ks + 8 * hi + i;
                    float val = (k < 64) ? (v[k] / ny)
                              : ((k == 64) ? mval : ((k == 65) ? 128.0f : 0.0f));
                    tmp.e[i] = (f16)val;
                }
                q4[cb + (size_t)ks * 64 + hi * 32 + r] = tmp.u;
            }
        }
    }
}

// ---------------------------------------------------------------------------
// Kernel 2: MFMA candidate pass. 2 n-subtiles per wave (halves panel loads,
// 2 independent MFMA chains per tile for latency hiding). Zero-C trick: the
// first MFMA of each chain takes a loop-invariant zero vector as C (D != C)
// -- no per-cell accumulator re-init. Branch-free med3 top-4 extraction with
// 10-bit (tile*16+reg) index packed into mantissa low bits (scores positive
// via bias channel -> f32 order == u32 order). Grid 49x8x2 = 784 blocks,
// all waves co-resident (~3 waves/SIMD).
// ---------------------------------------------------------------------------
#define LDA(dst, t) { _Pragma("unroll") \
    for (int ks = 0; ks < KS; ++ks) { \
        U16B u_; u_.u = fyb[((size_t)(t) * KS + ks) * 64]; dst[ks] = u_.h; } }

#define EXTRACT(acc, B1, B2, B3, B4, bse) { \
    _Pragma("unroll") \
    for (int r = 0; r < 16; ++r) { \
        u32 pb_ = (__float_as_uint(acc[r]) & VMASK) | ((bse) + (u32)r); \
        float p_ = __uint_as_float(pb_); \
        B4 = __builtin_amdgcn_fmed3f(p_, B3, B4); \
        B3 = __builtin_amdgcn_fmed3f(p_, B2, B3); \
        B2 = __builtin_amdgcn_fmed3f(p_, B1, B2); \
        B1 = fmaxf(p_, B1); } }

#define CELLS(a, t) { \
    f32x16 acc0, acc1; \
    acc0 = __builtin_amdgcn_mfma_f32_32x32x16_f16(a[0], bfr0[0], zvec, 0, 0, 0); \
    acc1 = __builtin_amdgcn_mfma_f32_32x32x16_f16(a[0], bfr1[0], zvec, 0, 0, 0); \
    acc0 = __builtin_amdgcn_mfma_f32_32x32x16_f16(a[1], bfr0[1], acc0, 0, 0, 0); \
    acc1 = __builtin_amdgcn_mfma_f32_32x32x16_f16(a[1], bfr1[1], acc1, 0, 0, 0); \
    acc0 = __builtin_amdgcn_mfma_f32_32x32x16_f16(a[2], bfr0[2], acc0, 0, 0, 0); \
    acc1 = __builtin_amdgcn_mfma_f32_32x32x16_f16(a[2], bfr1[2], acc1, 0, 0, 0); \
    acc0 = __builtin_amdgcn_mfma_f32_32x32x16_f16(a[3], bfr0[3], acc0, 0, 0, 0); \
    acc1 = __builtin_amdgcn_mfma_f32_32x32x16_f16(a[3], bfr1[3], acc1, 0, 0, 0); \
    acc0 = __builtin_amdgcn_mfma_f32_32x32x16_f16(a[4], bfr0[4], acc0, 0, 0, 0); \
    acc1 = __builtin_amdgcn_mfma_f32_32x32x16_f16(a[4], bfr1[4], acc1, 0, 0, 0); \
    u32 bse_ = (u32)((t) * 16); \
    EXTRACT(acc0, c1a, c2a, c3a, c4a, bse_); \
    EXTRACT(acc1, c1b, c2b, c3b, c4b, bse_); }

__global__ __launch_bounds__(256, 3)
void stage1(const f16* __restrict__ fxq, const f16* __restrict__ fynq,
            u32* __restrict__ cvals, u16* __restrict__ cidx) {
    const int tid = threadIdx.x;
    const int lane = tid & 63, w = tid >> 6;
    const int lo = lane & 31, hi = lane >> 5;
    const int nb = blockIdx.x;          // 0..48
    const int split = blockIdx.y;
    const int b = blockIdx.z;
    const int tbase = split * TPS;

    const uint4* fxq4 = (const uint4*)fxq;
    const uint4* fyb  = (const uint4*)fynq + ((size_t)(b * MT + tbase) * KS) * 64 + lane;

    // pack mask pinned in a VGPR so (bits & VMASK) | s_idx fuses to v_and_or_b32
    u32 VMASK;
    asm("v_mov_b32 %0, 0xFFFFFC00" : "=v"(VMASK));

    // resident B-fragments: fx for this wave's two n-subtiles
    const int nt0 = nb * 8 + w * 2;
    f16x8 bfr0[KS], bfr1[KS];
    #pragma unroll
    for (int ks = 0; ks < KS; ++ks) {
        U16B u0; u0.u = fxq4[((size_t)((b * NT + nt0) * KS + ks)) * 64 + lane];
        bfr0[ks] = u0.h;
        U16B u1; u1.u = fxq4[((size_t)((b * NT + nt0 + 1) * KS + ks)) * 64 + lane];
        bfr1[ks] = u1.h;
    }

    f32x16 zvec = {};   // loop-invariant C operand: no per-cell acc re-init

    float c1a = 0.f, c2a = 0.f, c3a = 0.f, c4a = 0.f;
    float c1b = 0.f, c2b = 0.f, c3b = 0.f, c4b = 0.f;

    f16x8 aA[KS], aB[KS];
    LDA(aA, 0);
    #pragma unroll 1
    for (int t = 0; t < TPS - 1; t += 2) {   // t = 0,2,...,46
        LDA(aB, t + 1);
        CELLS(aA, t);
        LDA(aA, t + 2);                      // t+2 <= 48, always valid
        CELLS(aB, t + 1);
    }
    CELLS(aA, TPS - 1);                      // tile 48

    // decode + write candidates for both subtiles: [b][n][split][hi][4]
    #pragma unroll
    for (int s = 0; s < 2; ++s) {
        float bs[4];
        if (s == 0) { bs[0] = c1a; bs[1] = c2a; bs[2] = c3a; bs[3] = c4a; }
        else        { bs[0] = c1b; bs[1] = c2b; bs[2] = c3b; bs[3] = c4b; }
        int n = (nt0 + s) * 32 + lo;
        size_t base = (((size_t)(b * N_ + n) * SPLIT + split) * 2 + hi) * LCAP;
        #pragma unroll
        for (int k = 0; k < 4; ++k) {
            u32 pb = __float_as_uint(bs[k]);
            int idx10 = (int)(pb & 1023u);
            int tl = idx10 >> 4, r = idx10 & 15;
            int m = (tbase + tl) * 32 + (r & 3) + ((r >> 2) << 3) + (hi << 2);
            cvals[base + k] = pb;
            cidx[base + k] = (u16)m;
        }
    }
}

// ---------------------------------------------------------------------------
// Kernel 3: selective exact rescore. One wave per row, 1 candidate/lane.
// 3 wave-max rounds on noisy packed values -> t3; lanes with
// vn >= t3 - 0.125 (noise+grain ~0.04, 3x margin) recompute the
// bit-identical round-1 fp32 dot from contiguous fxT/fynT rows. Exact
// selection (tie: lower index) + exact weights -> absmax 0 preserved.
// ---------------------------------------------------------------------------
__global__ __launch_bounds__(256)
void rescore(const u32* __restrict__ cvals, const u16* __restrict__ cidx,
             const float* __restrict__ fxT, const float* __restrict__ fynT,
             const float* __restrict__ nyeps, const float* __restrict__ minf,
             const unsigned char* __restrict__ mask1b,
             const int* __restrict__ flags, float* __restrict__ out) {
    int gw = blockIdx.x * 4 + (threadIdx.x >> 6);    // row = b*N + n  (grid exact)
    int lane = threadIdx.x & 63;
    int b = gw / N_;

    float vn = __uint_as_float(cvals[(size_t)gw * CPR + lane]);
    int idx = cidx[(size_t)gw * CPR + lane];

    float cur = vn;
    float t3 = NEGINF;
    #pragma unroll
    for (int r = 0; r < 3; ++r) {
        float c = cur;
        #pragma unroll
        for (int off = 32; off >= 1; off >>= 1) c = fmaxf(c, __shfl_xor(c, off));
        t3 = c;
        cur = (cur == c) ? NEGINF : cur;
    }
    bool redo = (vn >= t3 - 0.125f);

    float rnk = NEGINF, wgt = 0.f;
    if (redo) {
        const float4* xq4 = (const float4*)(fxT + (size_t)gw * C_);
        const float4* fr4 = (const float4*)(fynT + ((size_t)b * N_ + idx) * C_);
        float a = 0.f;
        #pragma unroll
        for (int c4 = 0; c4 < 16; ++c4) {
            float4 xf = xq4[c4];
            float4 f  = fr4[c4];
            a = fmaf(xf.x, f.x, a);
            a = fmaf(xf.y, f.y, a);
            a = fmaf(xf.z, f.z, a);
            a = fmaf(xf.w, f.w, a);
        }
        rnk = a + minf[(size_t)b * N_ + idx];
        wgt = a * nyeps[(size_t)b * N_ + idx];
    }
    int midx = redo ? idx : 0x7fffffff;

    int wi[3]; float ww[3];
    #pragma unroll
    for (int r = 0; r < 3; ++r) {
        float cv = rnk; int ci = midx; float cw = wgt;
        #pragma unroll
        for (int off = 32; off >= 1; off >>= 1) {
            float ov = __shfl_xor(cv, off);
            int   oi = __shfl_xor(ci, off);
            float ow = __shfl_xor(cw, off);
            bool take = (ov > cv) || (ov == cv && oi < ci);
            cv = take ? ov : cv; ci = take ? oi : ci; cw = take ? ow : cw;
        }
        wi[r] = ci; ww[r] = cw;
        if (midx == ci) rnk = NEGINF;   // remove winner (and duplicates)
    }

    if (lane == 0) {
        float w0 = ww[0], w1 = ww[1], w2 = ww[2];
        float h0 = (float)(wi[0] / W_), h1 = (float)(wi[1] / W_), h2 = (float)(wi[2] / W_);
        float q0 = (float)(wi[0] % W_), q1 = (float)(wi[1] % W_), q2 = (float)(wi[2] % W_);
        float den = w0 + w1 + w2;
        float ph = (h0 * w0 + h1 * w1 + h2 * w2) / den;
        float pw = (q0 * w0 + q1 * w1 + q2 * w2) / den;
        bool m1 = flags[0] ? (mask1b[gw] != 0) : (((const int*)mask1b)[gw] != 0);
        out[2 * gw]     = m1 ? ph : -1.0f;
        out[2 * gw + 1] = m1 ? pw : -1.0f;
    }
}

// ---------------------------------------------------------------------------
// Kernel 4: slic gather.
// ---------------------------------------------------------------------------
__global__ void slic_gather(const float* __restrict__ spg,
                            const float* __restrict__ pred,
                            float* __restrict__ outg) {
    int t = blockIdx.x * blockDim.x + threadIdx.x;
    if (t >= B_ * S_ * G_) return;
    int b = t / (S_ * G_);
    float vh = spg[2 * t], vw = spg[2 * t + 1];
    int ph = (int)rintf(vh * (float)H_);
    int pw = (int)rintf(vw * (float)H_);
    ph = ph < 0 ? 0 : (ph > H_ - 1 ? H_ - 1 : ph);
    pw = pw < 0 ? 0 : (pw > H_ - 1 ? H_ - 1 : pw);
    int lin = ph * W_ + pw;
    outg[2 * t]     = pred[((size_t)b * N_ + lin) * 2]     / (float)H_;
    outg[2 * t + 1] = pred[((size_t)b * N_ + lin) * 2 + 1] / (float)H_;
}

extern "C" void kernel_launch(void* const* d_in, const int* in_sizes, int n_in,
                              void* d_out, int out_size, void* d_ws, size_t ws_size,
                              hipStream_t stream) {
    const float* img1 = (const float*)d_in[0];
    const float* img2 = (const float*)d_in[1];
    const void*  mask1 = d_in[2];
    const void*  mask2 = d_in[3];
    const float* spg = (const float*)d_in[4];
    float* out = (float*)d_out;

    char* ws = (char*)d_ws;
    size_t off = 0;
    int*   flags = (int*)(ws + off);            off += 256;
    float* fynT  = (float*)(ws + off);          off += (size_t)B_ * N_ * C_ * 4;       // 6.42 MB
    float* fxT   = (float*)(ws + off);          off += (size_t)B_ * N_ * C_ * 4;       // 6.42 MB
    f16*   fxq   = (f16*)(ws + off);            off += (size_t)B_ * NT * KS * 64 * 16; // 4.01 MB
    f16*   fynq  = (f16*)(ws + off);            off += (size_t)B_ * MT * KS * 64 * 16; // 4.01 MB
    float* nyeps = (float*)(ws + off);          off += (size_t)B_ * N_ * 4;
    float* minf  = (float*)(ws + off);          off += (size_t)B_ * N_ * 4;
    u32*   cvals = (u32*)(ws + off);            off += (size_t)B_ * N_ * CPR * 4;      // 6.42 MB
    u16*   cidx  = (u16*)(ws + off);            off += (size_t)B_ * N_ * CPR * 2;      // 3.21 MB

    detect_fmt<<<1, 1024, 0, stream>>>((const u32*)mask1, (const u32*)mask2,
                                       (B_ * N_) / 4, flags);
    dim3 gp((B_ * N_) / 256, 2);
    prep<<<gp, 256, 0, stream>>>(img1, img2, (const unsigned char*)mask2, flags,
                                 fxq, fxT, fynT, fynq, nyeps, minf);

    dim3 g1(49, SPLIT, B_);
    stage1<<<g1, 256, 0, stream>>>(fxq, fynq, cvals, cidx);

    rescore<<<(B_ * N_) / 4, 256, 0, stream>>>(
        cvals, cidx, fxT, fynT, nyeps, minf,
        (const unsigned char*)mask1, flags, out);

    slic_gather<<<(B_ * S_ * G_ + 255) / 256, 256, 0, stream>>>(
        spg, out, out + (size_t)B_ * N_ * 2);
}

// Round 10
// 147.732 us; speedup vs baseline: 1.0427x; 1.0420x over previous
//
#include <hip/hip_runtime.h>
#include <math.h>

typedef _Float16 f16;
typedef f16 f16x8 __attribute__((ext_vector_type(8)));
typedef float f32x16 __attribute__((ext_vector_type(16)));
typedef unsigned short u16;
typedef unsigned int u32;

#define B_ 2
#define C_ 64
#define KS 5             // K-steps of 16: 64 feats + mask(k=64) + bias(k=65) + pad
#define H_ 112
#define W_ 112
#define N_ 12544
#define S_ 50
#define G_ 120
#define MT 392           // m-tiles of 32
#define NT 392           // n-subtiles of 32
#define SPLIT 8
#define TPS 49           // m-tiles per split
#define LCAP 4           // per-lane-half top-4 (exact, branch-free)
#define CPR (SPLIT*2*LCAP) // 64 candidates per row -> 1 per lane in rescore

#define NEGINF (-__builtin_inff())

union U16B { uint4 u; f16x8 h; f16 e[8]; };

// ---------------------------------------------------------------------------
// Kernel 0: bool-mask format detect (byte vs int32), vectorized word test.
// ---------------------------------------------------------------------------
__global__ void detect_fmt(const u32* __restrict__ m1, const u32* __restrict__ m2,
                           int nw, int* __restrict__ flags) {
    __shared__ u32 s[2];
    if (threadIdx.x == 0) { s[0] = 0; s[1] = 0; }
    __syncthreads();
    u32 a = 0, bb = 0;
    for (int i = threadIdx.x; i < nw; i += blockDim.x) {
        a  |= m1[i] & 0xFFFFFF00u;
        bb |= m2[i] & 0xFFFFFF00u;
    }
    if (a)  atomicOr(&s[0], 1u);
    if (bb) atomicOr(&s[1], 1u);
    __syncthreads();
    if (threadIdx.x == 0) { flags[0] = s[0] ? 1 : 0; flags[1] = s[1] ? 1 : 0; }
}

// ---------------------------------------------------------------------------
// Kernel 1 (fused): y==0 -> src features: fp16 frag-ordered fxq (k=64/65
// channels = 1.0) AND contiguous fp32 fxT rows. y==1 -> dst features: fp32
// fynT rows (bitwise same math as round 1), fp16 frag-ordered fynq with
// mask channel (k=64: 0 valid / -96 masked) and bias channel (k=65: +128),
// nyeps, minf.
// ---------------------------------------------------------------------------
__global__ void prep(const float* __restrict__ fx, const float* __restrict__ fy,
                     const unsigned char* __restrict__ mask2b,
                     const int* __restrict__ flags,
                     f16* __restrict__ fxq, float* __restrict__ fxT,
                     float* __restrict__ fynT, f16* __restrict__ fynq,
                     float* __restrict__ nyeps, float* __restrict__ minf) {
    int t = blockIdx.x * blockDim.x + threadIdx.x;   // t = b*N + pixel
    if (t >= B_ * N_) return;
    int b = t / N_, m = t - b * N_;
    int tile = m >> 5, r = m & 31;

    if (blockIdx.y == 0) {
        const float* src = fx + (size_t)b * C_ * N_ + m;
        float v[64];
        #pragma unroll
        for (int c = 0; c < C_; ++c) v[c] = src[(size_t)c * N_];

        float4* xT = (float4*)(fxT + (size_t)t * C_);
        #pragma unroll
        for (int c4 = 0; c4 < 16; ++c4)
            xT[c4] = make_float4(v[c4*4], v[c4*4+1], v[c4*4+2], v[c4*4+3]);

        uint4* q4 = (uint4*)fxq;
        size_t cb = (size_t)(b * NT + tile) * KS * 64;
        #pragma unroll
        for (int ks = 0; ks < KS; ++ks) {
            #pragma unroll
            for (int hi = 0; hi < 2; ++hi) {
                U16B tmp;
                #pragma unroll
                for (int i = 0; i < 8; ++i) {
                    int k = 16 * ks + 8 * hi + i;
                    float val = (k < 64) ? v[k] : ((k <= 65) ? 1.0f : 0.0f);
                    tmp.e[i] = (f16)val;
                }
                q4[cb + (size_t)ks * 64 + hi * 32 + r] = tmp.u;
            }
        }
    } else {
        const float* src = fy + (size_t)b * C_ * N_ + m;
        float v[64];
        float ss = 0.f;
        #pragma unroll
        for (int c = 0; c < C_; ++c) { v[c] = src[(size_t)c * N_]; ss = fmaf(v[c], v[c], ss); }
        float ny = sqrtf(ss) + 1e-12f;
        nyeps[t] = ny;
        bool valid = flags[1] ? (mask2b[t] != 0) : (((const int*)mask2b)[t] != 0);
        minf[t] = valid ? 0.0f : NEGINF;
        float mval = valid ? 0.0f : -96.0f;

        float* dT = fynT + (size_t)t * C_;
        #pragma unroll
        for (int c = 0; c < C_; ++c) dT[c] = v[c] / ny;   // round-1 arithmetic

        uint4* q4 = (uint4*)fynq;
        size_t cb = (size_t)(b * MT + tile) * KS * 64;
        #pragma unroll
        for (int ks = 0; ks < KS; ++ks) {
            #pragma unroll
            for (int hi = 0; hi < 2; ++hi) {
                U16B tmp;
                #pragma unroll
                for (int i = 0; i < 8; ++i) {
                    int k = 16 * ks + 8 * hi + i;
                    float val = (k < 64) ? (v[k] / ny)
                              : ((k == 64) ? mval : ((k == 65) ? 128.0f : 0.0f));
                    tmp.e[i] = (f16)val;
                }
                q4[cb + (size_t)ks * 64 + hi * 32 + r] = tmp.u;
            }
        }
    }
}

// ---------------------------------------------------------------------------
// Kernel 2: MFMA candidate pass. Wave-granular: 3136 blocks x 128 threads
// (2 waves, 1 n-subtile each). Flat grid with panel = gid & 15: since
// blockIdx round-robins XCDs, panel p only ever runs on XCD p%8 -> each
// XCD L2 serves exactly 2 panels (490 KB, L2-resident) -> A-tile loads are
// L2 hits instead of cross-die refetches. Double-buffered A (named regs),
// zero-C MFMA start, branch-free med3 top-4 extraction with 10-bit
// (tile*16+reg) index packed into mantissa low bits. launch_bounds(128,5)
// caps VGPR at ~102 so 5 waves/SIMD can be resident to fill latency holes.
// ---------------------------------------------------------------------------
#define LDA(dst, t) { _Pragma("unroll") \
    for (int ks = 0; ks < KS; ++ks) { \
        U16B u_; u_.u = fyb[((size_t)(t) * KS + ks) * 64]; dst[ks] = u_.h; } }

#define EXTRACT(acc, bse) { \
    _Pragma("unroll") \
    for (int r = 0; r < 16; ++r) { \
        u32 pb_ = (__float_as_uint(acc[r]) & VMASK) | ((bse) + (u32)r); \
        float p_ = __uint_as_float(pb_); \
        b4 = __builtin_amdgcn_fmed3f(p_, b3, b4); \
        b3 = __builtin_amdgcn_fmed3f(p_, b2, b3); \
        b2 = __builtin_amdgcn_fmed3f(p_, b1, b2); \
        b1 = fmaxf(p_, b1); } }

#define CELL(a, t) { \
    f32x16 acc; \
    acc = __builtin_amdgcn_mfma_f32_32x32x16_f16(a[0], bfr[0], zvec, 0, 0, 0); \
    acc = __builtin_amdgcn_mfma_f32_32x32x16_f16(a[1], bfr[1], acc, 0, 0, 0); \
    acc = __builtin_amdgcn_mfma_f32_32x32x16_f16(a[2], bfr[2], acc, 0, 0, 0); \
    acc = __builtin_amdgcn_mfma_f32_32x32x16_f16(a[3], bfr[3], acc, 0, 0, 0); \
    acc = __builtin_amdgcn_mfma_f32_32x32x16_f16(a[4], bfr[4], acc, 0, 0, 0); \
    EXTRACT(acc, (u32)((t) * 16)); }

__global__ __launch_bounds__(128, 5)
void stage1(const f16* __restrict__ fxq, const f16* __restrict__ fynq,
            u32* __restrict__ cvals, u16* __restrict__ cidx) {
    const int tid = threadIdx.x;
    const int lane = tid & 63, w = tid >> 6;
    const int lo = lane & 31, hi = lane >> 5;
    const int gid = blockIdx.x;          // 0..3135
    const int panel = gid & 15;          // (b<<3)|split -> XCD affinity
    const int b = panel >> 3, split = panel & 7;
    const int nt = (gid >> 4) * 2 + w;   // 0..391
    const int tbase = split * TPS;

    const uint4* fxq4 = (const uint4*)fxq;
    const uint4* fyb  = (const uint4*)fynq + ((size_t)(b * MT + tbase) * KS) * 64 + lane;

    // pack mask pinned in a VGPR so (bits & VMASK) | s_idx fuses to v_and_or_b32
    u32 VMASK;
    asm("v_mov_b32 %0, 0xFFFFFC00" : "=v"(VMASK));

    // resident B-fragments: fx for this wave's n-subtile
    f16x8 bfr[KS];
    #pragma unroll
    for (int ks = 0; ks < KS; ++ks) {
        U16B u; u.u = fxq4[((size_t)((b * NT + nt) * KS + ks)) * 64 + lane];
        bfr[ks] = u.h;
    }

    f32x16 zvec = {};   // loop-invariant C operand: no per-cell acc re-init

    float b1 = 0.f, b2 = 0.f, b3 = 0.f, b4 = 0.f;

    f16x8 aA[KS], aB[KS];
    LDA(aA, 0);
    #pragma unroll 1
    for (int t = 0; t < TPS - 1; t += 2) {   // t = 0,2,...,46
        LDA(aB, t + 1);
        CELL(aA, t);
        LDA(aA, t + 2);                      // t+2 <= 48, always valid
        CELL(aB, t + 1);
    }
    CELL(aA, TPS - 1);                       // tile 48

    // decode + write candidates: [b][n][split][hi][4]
    int n = nt * 32 + lo;
    size_t base = (((size_t)(b * N_ + n) * SPLIT + split) * 2 + hi) * LCAP;
    float bs[4] = {b1, b2, b3, b4};
    #pragma unroll
    for (int k = 0; k < 4; ++k) {
        u32 pb = __float_as_uint(bs[k]);
        int idx10 = (int)(pb & 1023u);
        int tl = idx10 >> 4, r = idx10 & 15;
        int m = (tbase + tl) * 32 + (r & 3) + ((r >> 2) << 3) + (hi << 2);
        cvals[base + k] = pb;
        cidx[base + k] = (u16)m;
    }
}

// ---------------------------------------------------------------------------
// Kernel 3: selective exact rescore. One wave per row, 1 candidate/lane.
// 3 wave-max rounds on noisy packed values -> t3; lanes with
// vn >= t3 - 0.125 (noise+grain ~0.04, 3x margin) recompute the
// bit-identical round-1 fp32 dot from contiguous fxT/fynT rows. Exact
// selection (tie: lower index) + exact weights -> absmax 0 preserved.
// ---------------------------------------------------------------------------
__global__ __launch_bounds__(256)
void rescore(const u32* __restrict__ cvals, const u16* __restrict__ cidx,
             const float* __restrict__ fxT, const float* __restrict__ fynT,
             const float* __restrict__ nyeps, const float* __restrict__ minf,
             const unsigned char* __restrict__ mask1b,
             const int* __restrict__ flags, float* __restrict__ out) {
    int gw = blockIdx.x * 4 + (threadIdx.x >> 6);    // row = b*N + n  (grid exact)
    int lane = threadIdx.x & 63;
    int b = gw / N_;

    float vn = __uint_as_float(cvals[(size_t)gw * CPR + lane]);
    int idx = cidx[(size_t)gw * CPR + lane];

    float cur = vn;
    float t3 = NEGINF;
    #pragma unroll
    for (int r = 0; r < 3; ++r) {
        float c = cur;
        #pragma unroll
        for (int off = 32; off >= 1; off >>= 1) c = fmaxf(c, __shfl_xor(c, off));
        t3 = c;
        cur = (cur == c) ? NEGINF : cur;
    }
    bool redo = (vn >= t3 - 0.125f);

    float rnk = NEGINF, wgt = 0.f;
    if (redo) {
        const float4* xq4 = (const float4*)(fxT + (size_t)gw * C_);
        const float4* fr4 = (const float4*)(fynT + ((size_t)b * N_ + idx) * C_);
        float a = 0.f;
        #pragma unroll
        for (int c4 = 0; c4 < 16; ++c4) {
            float4 xf = xq4[c4];
            float4 f  = fr4[c4];
            a = fmaf(xf.x, f.x, a);
            a = fmaf(xf.y, f.y, a);
            a = fmaf(xf.z, f.z, a);
            a = fmaf(xf.w, f.w, a);
        }
        rnk = a + minf[(size_t)b * N_ + idx];
        wgt = a * nyeps[(size_t)b * N_ + idx];
    }
    int midx = redo ? idx : 0x7fffffff;

    int wi[3]; float ww[3];
    #pragma unroll
    for (int r = 0; r < 3; ++r) {
        float cv = rnk; int ci = midx; float cw = wgt;
        #pragma unroll
        for (int off = 32; off >= 1; off >>= 1) {
            float ov = __shfl_xor(cv, off);
            int   oi = __shfl_xor(ci, off);
            float ow = __shfl_xor(cw, off);
            bool take = (ov > cv) || (ov == cv && oi < ci);
            cv = take ? ov : cv; ci = take ? oi : ci; cw = take ? ow : cw;
        }
        wi[r] = ci; ww[r] = cw;
        if (midx == ci) rnk = NEGINF;   // remove winner (and duplicates)
    }

    if (lane == 0) {
        float w0 = ww[0], w1 = ww[1], w2 = ww[2];
        float h0 = (float)(wi[0] / W_), h1 = (float)(wi[1] / W_), h2 = (float)(wi[2] / W_);
        float q0 = (float)(wi[0] % W_), q1 = (float)(wi[1] % W_), q2 = (float)(wi[2] % W_);
        float den = w0 + w1 + w2;
        float ph = (h0 * w0 + h1 * w1 + h2 * w2) / den;
        float pw = (q0 * w0 + q1 * w1 + q2 * w2) / den;
        bool m1 = flags[0] ? (mask1b[gw] != 0) : (((const int*)mask1b)[gw] != 0);
        out[2 * gw]     = m1 ? ph : -1.0f;
        out[2 * gw + 1] = m1 ? pw : -1.0f;
    }
}

// ---------------------------------------------------------------------------
// Kernel 4: slic gather.
// ---------------------------------------------------------------------------
__global__ void slic_gather(const float* __restrict__ spg,
                            const float* __restrict__ pred,
                            float* __restrict__ outg) {
    int t = blockIdx.x * blockDim.x + threadIdx.x;
    if (t >= B_ * S_ * G_) return;
    int b = t / (S_ * G_);
    float vh = spg[2 * t], vw = spg[2 * t + 1];
    int ph = (int)rintf(vh * (float)H_);
    int pw = (int)rintf(vw * (float)H_);
    ph = ph < 0 ? 0 : (ph > H_ - 1 ? H_ - 1 : ph);
    pw = pw < 0 ? 0 : (pw > H_ - 1 ? H_ - 1 : pw);
    int lin = ph * W_ + pw;
    outg[2 * t]     = pred[((size_t)b * N_ + lin) * 2]     / (float)H_;
    outg[2 * t + 1] = pred[((size_t)b * N_ + lin) * 2 + 1] / (float)H_;
}

extern "C" void kernel_launch(void* const* d_in, const int* in_sizes, int n_in,
                              void* d_out, int out_size, void* d_ws, size_t ws_size,
                              hipStream_t stream) {
    const float* img1 = (const float*)d_in[0];
    const float* img2 = (const float*)d_in[1];
    const void*  mask1 = d_in[2];
    const void*  mask2 = d_in[3];
    const float* spg = (const float*)d_in[4];
    float* out = (float*)d_out;

    char* ws = (char*)d_ws;
    size_t off = 0;
    int*   flags = (int*)(ws + off);            off += 256;
    float* fynT  = (float*)(ws + off);          off += (size_t)B_ * N_ * C_ * 4;       // 6.42 MB
    float* fxT   = (float*)(ws + off);          off += (size_t)B_ * N_ * C_ * 4;       // 6.42 MB
    f16*   fxq   = (f16*)(ws + off);            off += (size_t)B_ * NT * KS * 64 * 16; // 4.01 MB
    f16*   fynq  = (f16*)(ws + off);            off += (size_t)B_ * MT * KS * 64 * 16; // 4.01 MB
    float* nyeps = (float*)(ws + off);          off += (size_t)B_ * N_ * 4;
    float* minf  = (float*)(ws + off);          off += (size_t)B_ * N_ * 4;
    u32*   cvals = (u32*)(ws + off);            off += (size_t)B_ * N_ * CPR * 4;      // 6.42 MB
    u16*   cidx  = (u16*)(ws + off);            off += (size_t)B_ * N_ * CPR * 2;      // 3.21 MB

    detect_fmt<<<1, 1024, 0, stream>>>((const u32*)mask1, (const u32*)mask2,
                                       (B_ * N_) / 4, flags);
    dim3 gp((B_ * N_) / 256, 2);
    prep<<<gp, 256, 0, stream>>>(img1, img2, (const unsigned char*)mask2, flags,
                                 fxq, fxT, fynT, fynq, nyeps, minf);

    stage1<<<3136, 128, 0, stream>>>(fxq, fynq, cvals, cidx);

    rescore<<<(B_ * N_) / 4, 256, 0, stream>>>(
        cvals, cidx, fxT, fynT, nyeps, minf,
        (const unsigned char*)mask1, flags, out);

    slic_gather<<<(B_ * S_ * G_ + 255) / 256, 256, 0, stream>>>(
        spg, out, out + (size_t)B_ * N_ * 2);
}